// Round 2
// baseline (9178.613 us; speedup 1.0000x reference)
//
#include <hip/hip_runtime.h>
#include <hip/hip_bf16.h>

#define B_   4
#define LD_  1024
#define LE_  1024
#define D_   256
#define H_   8
#define DK_  32
#define DFF_ 1024
#define NL_  6
#define NTOK (B_ * LD_)   // 4096 decoder tokens; encoder also 4*1024 = 4096

typedef __hip_bfloat16 bf16;

__device__ __forceinline__ float bits2f(unsigned short u) {
    union { unsigned int i; float f; } w; w.i = ((unsigned int)u) << 16; return w.f;
}
// dtype-flexible scalar load from tensor base + element index
__device__ __forceinline__ float ldx(const void* p, size_t i, int f32) {
    if (f32) return ((const float*)p)[i];
    return bits2f(((const unsigned short*)p)[i]);
}

// ---------------------------------------------------------------------------
// Detect input dtype. bf16 N(0,1) data never has exponent field >= 142
// (|x| >= 2^15); fp32 misread as bf16 exposes mantissa fragments with
// ~uniform exponent bits -> certain hit within 4096 samples.
__global__ __launch_bounds__(256) void detect_kernel(
    const void* __restrict__ enc, int* __restrict__ flag)
{
    __shared__ int bad;
    if (threadIdx.x == 0) bad = 0;
    __syncthreads();
    const unsigned short* u = (const unsigned short*)enc;
    int b = 0;
    for (int i = threadIdx.x; i < 4096; i += 256) {
        unsigned short e = (u[i] >> 7) & 0xFF;
        if (e >= 142) b = 1;
    }
    if (b) atomicOr(&bad, 1);
    __syncthreads();
    if (threadIdx.x == 0) *flag = bad;   // 1 => fp32 inputs, 0 => bf16 inputs
}

// ---------------------------------------------------------------------------
__global__ __launch_bounds__(256) void embed_kernel(
    const void* __restrict__ dec, const void* __restrict__ Wt,
    const void* __restrict__ bt, float* __restrict__ x, const int* __restrict__ flag)
{
    int f32 = *flag;
    int i = blockIdx.x * 256 + threadIdx.x;     // over NTOK * D_
    int d = i & (D_ - 1);
    int t = i >> 8;
    float a0 = ldx(dec, t * 3 + 0, f32);
    float a1 = ldx(dec, t * 3 + 1, f32);
    float a2 = ldx(dec, t * 3 + 2, f32);
    x[i] = ldx(bt, d, f32) + a0 * ldx(Wt, 0 * D_ + d, f32)
         + a1 * ldx(Wt, 1 * D_ + d, f32) + a2 * ldx(Wt, 2 * D_ + d, f32);
}

__global__ __launch_bounds__(256) void conv_kernel(
    const void* __restrict__ in, float* __restrict__ out, const int* __restrict__ flag)
{
    int f32 = *flag;
    int i = blockIdx.x * 256 + threadIdx.x;
    out[i] = ldx(in, i, f32);
}

__global__ __launch_bounds__(256) void add_pe_kernel(float* __restrict__ x)
{
    int i = blockIdx.x * 256 + threadIdx.x;
    int d = i & (D_ - 1);
    int tok = i >> 8;
    int pos = tok & (LD_ - 1);
    int j = d & 127;
    float inv = powf(10000.0f, -2.0f * (float)j / (float)D_);
    float s = (float)pos * inv;
    float pe = (d < 128) ? sinf(s) : cosf(s);
    x[i] += pe;
}

// ---------------------------------------------------------------------------
// C = A @ W + bias (optional relu). A fp32 [M,K]; W,bias dtype per flag;
// wOff/bOff are ELEMENT offsets of the layer slice within the weight tensor.
// z-batched over up to 3 independent (A,W,bias,C) tuples.
__global__ __launch_bounds__(256) void gemm3_kernel(
    const float* __restrict__ A0, const float* __restrict__ A1, const float* __restrict__ A2,
    const void* __restrict__ W0, const void* __restrict__ W1, const void* __restrict__ W2,
    const void* __restrict__ bias0, const void* __restrict__ bias1, const void* __restrict__ bias2,
    float* __restrict__ C0, float* __restrict__ C1, float* __restrict__ C2,
    size_t wOff, size_t bOff,
    int M, int N, int K, int relu, const int* __restrict__ flag)
{
    int f32 = *flag;
    int z = blockIdx.z;
    const float* A = (z == 0) ? A0 : (z == 1) ? A1 : A2;
    const void*  W = (z == 0) ? W0 : (z == 1) ? W1 : W2;
    const void*  bias = (z == 0) ? bias0 : (z == 1) ? bias1 : bias2;
    float* C = (z == 0) ? C0 : (z == 1) ? C1 : C2;

    __shared__ float As[64][20];
    __shared__ float Bs[16][68];

    int tid = threadIdx.x;
    int tx = tid & 15, ty = tid >> 4;
    int m0 = blockIdx.y * 64, n0 = blockIdx.x * 64;

    int arow = tid >> 2;            // 0..63
    int acol = (tid & 3) * 4;       // 0..12
    int brow = ty;                  // 0..15
    int bcol = tx * 4;              // 0..60

    float c[4][4] = {};

    for (int k0 = 0; k0 < K; k0 += 16) {
        float4 av = *(const float4*)&A[(size_t)(m0 + arow) * K + k0 + acol];
        size_t widx = wOff + (size_t)(k0 + brow) * N + n0 + bcol;
        float4 bv;
        if (f32) {
            bv = *(const float4*)((const float*)W + widx);
        } else {
            ushort4 wv = *(const ushort4*)((const unsigned short*)W + widx);
            bv = make_float4(bits2f(wv.x), bits2f(wv.y), bits2f(wv.z), bits2f(wv.w));
        }

        __syncthreads();
        *(float4*)&As[arow][acol] = av;
        *(float4*)&Bs[brow][bcol] = bv;
        __syncthreads();

#pragma unroll
        for (int k = 0; k < 16; ++k) {
            float a0 = As[ty][k], a1 = As[ty + 16][k], a2 = As[ty + 32][k], a3 = As[ty + 48][k];
            float b0 = Bs[k][tx], b1 = Bs[k][tx + 16], b2 = Bs[k][tx + 32], b3 = Bs[k][tx + 48];
            c[0][0] += a0 * b0; c[0][1] += a0 * b1; c[0][2] += a0 * b2; c[0][3] += a0 * b3;
            c[1][0] += a1 * b0; c[1][1] += a1 * b1; c[1][2] += a1 * b2; c[1][3] += a1 * b3;
            c[2][0] += a2 * b0; c[2][1] += a2 * b1; c[2][2] += a2 * b2; c[2][3] += a2 * b3;
            c[3][0] += a3 * b0; c[3][1] += a3 * b1; c[3][2] += a3 * b2; c[3][3] += a3 * b3;
        }
    }

#pragma unroll
    for (int i = 0; i < 4; ++i) {
        int m = m0 + ty + 16 * i;
#pragma unroll
        for (int j = 0; j < 4; ++j) {
            int n = n0 + tx + 16 * j;
            float v = c[i][j] + ldx(bias, bOff + n, f32);
            if (relu) v = fmaxf(v, 0.0f);
            C[(size_t)m * N + n] = v;
        }
    }
}

// ---------------------------------------------------------------------------
__global__ __launch_bounds__(256) void attn_kernel(
    const float* __restrict__ Q, const float* __restrict__ K,
    const float* __restrict__ V, float* __restrict__ O,
    const int* __restrict__ mask, int causal)
{
    __shared__ float sc[1024];
    __shared__ float red[256];
    __shared__ float4 wred[32];

    int tid = threadIdx.x;
    int qi = blockIdx.x, h = blockIdx.y, b = blockIdx.z;

    const float* qptr  = Q + ((size_t)(b * LD_ + qi)) * D_ + h * DK_;
    const float* kbase = K + ((size_t)b * LE_) * D_ + h * DK_;
    const float* vbase = V + ((size_t)b * LE_) * D_ + h * DK_;

    int g = tid & 7;      // d-group (4 floats each)
    int r = tid >> 3;     // 0..31

    float4 qv = *(const float4*)&qptr[g * 4];

    for (int it = 0; it < 32; ++it) {
        int s = it * 32 + r;
        float4 kv = *(const float4*)&kbase[(size_t)s * D_ + g * 4];
        float p = qv.x * kv.x + qv.y * kv.y + qv.z * kv.z + qv.w * kv.w;
        p += __shfl_xor(p, 1);
        p += __shfl_xor(p, 2);
        p += __shfl_xor(p, 4);
        if (g == 0) {
            bool msk = (causal && s > qi) || (mask[b * 1024 + s] != 0);
            sc[s] = msk ? -1e30f : p * 0.17677669529663687f;  // 1/sqrt(32)
        }
    }
    __syncthreads();

    float m = fmaxf(fmaxf(sc[tid], sc[tid + 256]), fmaxf(sc[tid + 512], sc[tid + 768]));
    red[tid] = m;
    __syncthreads();
    for (int off = 128; off > 0; off >>= 1) {
        if (tid < off) red[tid] = fmaxf(red[tid], red[tid + off]);
        __syncthreads();
    }
    float mx = red[0];
    __syncthreads();

    float e0 = __expf(sc[tid] - mx);
    float e1 = __expf(sc[tid + 256] - mx);
    float e2 = __expf(sc[tid + 512] - mx);
    float e3 = __expf(sc[tid + 768] - mx);
    sc[tid] = e0; sc[tid + 256] = e1; sc[tid + 512] = e2; sc[tid + 768] = e3;
    red[tid] = e0 + e1 + e2 + e3;
    __syncthreads();
    for (int off = 128; off > 0; off >>= 1) {
        if (tid < off) red[tid] += red[tid + off];
        __syncthreads();
    }
    float denom = red[0];
    __syncthreads();

    float4 a = make_float4(0.f, 0.f, 0.f, 0.f);
    for (int it = 0; it < 32; ++it) {
        int s = it * 32 + r;
        float p = sc[s];
        float4 vv = *(const float4*)&vbase[(size_t)s * D_ + g * 4];
        a.x += p * vv.x; a.y += p * vv.y; a.z += p * vv.z; a.w += p * vv.w;
    }
#pragma unroll
    for (int msk = 8; msk <= 32; msk <<= 1) {
        a.x += __shfl_xor(a.x, msk);
        a.y += __shfl_xor(a.y, msk);
        a.z += __shfl_xor(a.z, msk);
        a.w += __shfl_xor(a.w, msk);
    }
    if ((tid & 63) < 8) wred[(tid >> 6) * 8 + g] = a;
    __syncthreads();

    if (tid < 8) {
        float4 p0 = wred[tid], p1 = wred[8 + tid], p2 = wred[16 + tid], p3 = wred[24 + tid];
        float inv = 1.0f / denom;
        float4 o;
        o.x = (p0.x + p1.x + p2.x + p3.x) * inv;
        o.y = (p0.y + p1.y + p2.y + p3.y) * inv;
        o.z = (p0.z + p1.z + p2.z + p3.z) * inv;
        o.w = (p0.w + p1.w + p2.w + p3.w) * inv;
        *(float4*)&O[((size_t)(b * LD_ + qi)) * D_ + h * DK_ + tid * 4] = o;
    }
}

// ---------------------------------------------------------------------------
// x = LayerNorm(t + x) * g + b ; g/b dtype per flag, gbOff = element offset
__global__ __launch_bounds__(256) void ln_res_kernel(
    const float* __restrict__ t, float* __restrict__ x,
    const void* __restrict__ g, const void* __restrict__ bt,
    size_t gbOff, const int* __restrict__ flag)
{
    __shared__ float r1[256];
    __shared__ float r2[256];
    int f32 = *flag;
    int tok = blockIdx.x;
    int d = threadIdx.x;
    size_t idx = (size_t)tok * D_ + d;
    float v = t[idx] + x[idx];
    r1[d] = v; r2[d] = v * v;
    __syncthreads();
    for (int off = 128; off > 0; off >>= 1) {
        if (d < off) { r1[d] += r1[d + off]; r2[d] += r2[d + off]; }
        __syncthreads();
    }
    float mean = r1[0] * (1.0f / 256.0f);
    float var  = r2[0] * (1.0f / 256.0f) - mean * mean;
    float inv  = 1.0f / sqrtf(var + 1e-5f);
    x[idx] = (v - mean) * inv * ldx(g, gbOff + d, f32) + ldx(bt, gbOff + d, f32);
}

__global__ __launch_bounds__(256) void cast_kernel(
    const float* __restrict__ x, void* __restrict__ out, const int* __restrict__ flag)
{
    int f32 = *flag;
    int i = blockIdx.x * 256 + threadIdx.x;
    if (f32) ((float*)out)[i] = x[i];
    else ((bf16*)out)[i] = __float2bfloat16(x[i]);
}

// ---------------------------------------------------------------------------
extern "C" void kernel_launch(void* const* d_in, const int* in_sizes, int n_in,
                              void* d_out, int out_size, void* d_ws, size_t ws_size,
                              hipStream_t stream)
{
    const void* enc       = d_in[0];
    const void* dec       = d_in[1];
    const int*  enc_masks = (const int*)d_in[2];
    const int*  dec_masks = (const int*)d_in[3];
    const void* W_tgt = d_in[4];
    const void* b_tgt = d_in[5];
    const void* sa_Wq = d_in[6];
    const void* sa_bq = d_in[7];
    const void* sa_Wk = d_in[8];
    const void* sa_bk = d_in[9];
    const void* sa_Wv = d_in[10];
    const void* sa_bv = d_in[11];
    const void* sa_Wo = d_in[12];
    const void* sa_bo = d_in[13];
    const void* sa_ln_g = d_in[14];
    const void* sa_ln_b = d_in[15];
    const void* ca_Wq = d_in[16];
    const void* ca_bq = d_in[17];
    const void* ca_Wk = d_in[18];
    const void* ca_bk = d_in[19];
    const void* ca_Wv = d_in[20];
    const void* ca_bv = d_in[21];
    const void* ca_Wo = d_in[22];
    const void* ca_bo = d_in[23];
    const void* ca_ln_g = d_in[24];
    const void* ca_ln_b = d_in[25];
    const void* ff_W1 = d_in[26];
    const void* ff_b1 = d_in[27];
    const void* ff_W2 = d_in[28];
    const void* ff_b2 = d_in[29];
    const void* ff_ln_g = d_in[30];
    const void* ff_ln_b = d_in[31];

    const size_t M1 = (size_t)NTOK * D_;        // 1M floats
    float* ws = (float*)d_ws;
    float* x     = ws;
    float* q     = ws + 1 * M1;
    float* k     = ws + 2 * M1;
    float* v     = ws + 3 * M1;
    float* ctx   = ws + 4 * M1;
    float* t     = ws + 5 * M1;
    float* h     = ws + 6 * M1;                 // 4M floats (NTOK x DFF)
    float* enc_f = ws + 10 * M1;
    int*   flag  = (int*)(ws + 11 * M1);

    const int nElem = NTOK * D_;                // 1,048,576

    detect_kernel<<<1, 256, 0, stream>>>(enc, flag);
    embed_kernel<<<nElem / 256, 256, 0, stream>>>(dec, W_tgt, b_tgt, x, flag);
    conv_kernel<<<nElem / 256, 256, 0, stream>>>(enc, enc_f, flag);

    dim3 gProj(D_ / 64, NTOK / 64, 3);          // (4,64,3)
    dim3 gOne(D_ / 64, NTOK / 64, 1);           // (4,64,1)
    dim3 gFF1(DFF_ / 64, NTOK / 64, 1);         // (16,64,1)
    dim3 gAttn(LD_, H_, B_);                    // (1024,8,4)

    for (int i = 0; i < NL_; ++i) {
        const size_t wOff  = (size_t)i * D_ * D_;      // element offsets
        const size_t bOff  = (size_t)i * D_;
        const size_t f1Off = (size_t)i * D_ * DFF_;
        const size_t f1bOff= (size_t)i * DFF_;

        add_pe_kernel<<<nElem / 256, 256, 0, stream>>>(x);

        // --- self attention ---
        gemm3_kernel<<<gProj, 256, 0, stream>>>(
            x, x, x, sa_Wq, sa_Wk, sa_Wv, sa_bq, sa_bk, sa_bv,
            q, k, v, wOff, bOff, NTOK, D_, D_, 0, flag);
        attn_kernel<<<gAttn, 256, 0, stream>>>(q, k, v, ctx, dec_masks, 1);
        gemm3_kernel<<<gOne, 256, 0, stream>>>(
            ctx, ctx, ctx, sa_Wo, sa_Wo, sa_Wo, sa_bo, sa_bo, sa_bo,
            t, t, t, wOff, bOff, NTOK, D_, D_, 0, flag);
        ln_res_kernel<<<NTOK, 256, 0, stream>>>(t, x, sa_ln_g, sa_ln_b, bOff, flag);

        // --- cross attention ---
        gemm3_kernel<<<gProj, 256, 0, stream>>>(
            x, enc_f, enc_f, ca_Wq, ca_Wk, ca_Wv, ca_bq, ca_bk, ca_bv,
            q, k, v, wOff, bOff, NTOK, D_, D_, 0, flag);
        attn_kernel<<<gAttn, 256, 0, stream>>>(q, k, v, ctx, enc_masks, 0);
        gemm3_kernel<<<gOne, 256, 0, stream>>>(
            ctx, ctx, ctx, ca_Wo, ca_Wo, ca_Wo, ca_bo, ca_bo, ca_bo,
            t, t, t, wOff, bOff, NTOK, D_, D_, 0, flag);
        ln_res_kernel<<<NTOK, 256, 0, stream>>>(t, x, ca_ln_g, ca_ln_b, bOff, flag);

        // --- FFN ---
        gemm3_kernel<<<gFF1, 256, 0, stream>>>(
            x, x, x, ff_W1, ff_W1, ff_W1, ff_b1, ff_b1, ff_b1,
            h, h, h, f1Off, f1bOff, NTOK, DFF_, D_, 1, flag);
        gemm3_kernel<<<gOne, 256, 0, stream>>>(
            h, h, h, ff_W2, ff_W2, ff_W2, ff_b2, ff_b2, ff_b2,
            t, t, t, f1Off, bOff, NTOK, D_, DFF_, 0, flag);
        ln_res_kernel<<<NTOK, 256, 0, stream>>>(t, x, ff_ln_g, ff_ln_b, bOff, flag);
    }

    cast_kernel<<<nElem / 256, 256, 0, stream>>>(x, d_out, flag);
}

// Round 3
// 3548.645 us; speedup vs baseline: 2.5865x; 2.5865x over previous
//
#include <hip/hip_runtime.h>
#include <hip/hip_bf16.h>

#define B_   4
#define LD_  1024
#define LE_  1024
#define D_   256
#define H_   8
#define DK_  32
#define DFF_ 1024
#define NL_  6
#define NTOK (B_ * LD_)   // 4096 decoder tokens; encoder also 4*1024 = 4096

typedef __hip_bfloat16 bf16;

__device__ __forceinline__ float bits2f(unsigned short u) {
    union { unsigned int i; float f; } w; w.i = ((unsigned int)u) << 16; return w.f;
}
// dtype-flexible scalar load from tensor base + element index
__device__ __forceinline__ float ldx(const void* p, size_t i, int f32) {
    if (f32) return ((const float*)p)[i];
    return bits2f(((const unsigned short*)p)[i]);
}
__device__ __forceinline__ float dot4(float4 a, float4 b) {
    return a.x * b.x + a.y * b.y + a.z * b.z + a.w * b.w;
}

// ---------------------------------------------------------------------------
// Detect input dtype (bf16 vs fp32) — see round-1 notes. flag: 1=fp32, 0=bf16.
__global__ __launch_bounds__(256) void detect_kernel(
    const void* __restrict__ enc, int* __restrict__ flag)
{
    __shared__ int bad;
    if (threadIdx.x == 0) bad = 0;
    __syncthreads();
    const unsigned short* u = (const unsigned short*)enc;
    int b = 0;
    for (int i = threadIdx.x; i < 4096; i += 256) {
        unsigned short e = (u[i] >> 7) & 0xFF;
        if (e >= 142) b = 1;
    }
    if (b) atomicOr(&bad, 1);
    __syncthreads();
    if (threadIdx.x == 0) *flag = bad;
}

// ---------------------------------------------------------------------------
__global__ __launch_bounds__(256) void embed_kernel(
    const void* __restrict__ dec, const void* __restrict__ Wt,
    const void* __restrict__ bt, float* __restrict__ x, const int* __restrict__ flag)
{
    int f32 = *flag;
    int i = blockIdx.x * 256 + threadIdx.x;     // over NTOK * D_
    int d = i & (D_ - 1);
    int t = i >> 8;
    float a0 = ldx(dec, t * 3 + 0, f32);
    float a1 = ldx(dec, t * 3 + 1, f32);
    float a2 = ldx(dec, t * 3 + 2, f32);
    x[i] = ldx(bt, d, f32) + a0 * ldx(Wt, 0 * D_ + d, f32)
         + a1 * ldx(Wt, 1 * D_ + d, f32) + a2 * ldx(Wt, 2 * D_ + d, f32);
}

__global__ __launch_bounds__(256) void conv_kernel(
    const void* __restrict__ in, float* __restrict__ out, const int* __restrict__ flag)
{
    int f32 = *flag;
    int i = blockIdx.x * 256 + threadIdx.x;
    out[i] = ldx(in, i, f32);
}

__global__ __launch_bounds__(256) void add_pe_kernel(float* __restrict__ x)
{
    int i = blockIdx.x * 256 + threadIdx.x;
    int d = i & (D_ - 1);
    int tok = i >> 8;
    int pos = tok & (LD_ - 1);
    int j = d & 127;
    float inv = powf(10000.0f, -2.0f * (float)j / (float)D_);
    float s = (float)pos * inv;
    float pe = (d < 128) ? sinf(s) : cosf(s);
    x[i] += pe;
}

// ---------------------------------------------------------------------------
// C = A @ W + bias (optional relu). A fp32 [M,K]; W,bias dtype per flag;
// wOff/bOff are ELEMENT offsets of the layer slice within the weight tensor.
// z-batched over up to 3 independent (A,W,bias,C) tuples.
__global__ __launch_bounds__(256) void gemm3_kernel(
    const float* __restrict__ A0, const float* __restrict__ A1, const float* __restrict__ A2,
    const void* __restrict__ W0, const void* __restrict__ W1, const void* __restrict__ W2,
    const void* __restrict__ bias0, const void* __restrict__ bias1, const void* __restrict__ bias2,
    float* __restrict__ C0, float* __restrict__ C1, float* __restrict__ C2,
    size_t wOff, size_t bOff,
    int M, int N, int K, int relu, const int* __restrict__ flag)
{
    int f32 = *flag;
    int z = blockIdx.z;
    const float* A = (z == 0) ? A0 : (z == 1) ? A1 : A2;
    const void*  W = (z == 0) ? W0 : (z == 1) ? W1 : W2;
    const void*  bias = (z == 0) ? bias0 : (z == 1) ? bias1 : bias2;
    float* C = (z == 0) ? C0 : (z == 1) ? C1 : C2;

    __shared__ float As[64][20];
    __shared__ float Bs[16][68];

    int tid = threadIdx.x;
    int tx = tid & 15, ty = tid >> 4;
    int m0 = blockIdx.y * 64, n0 = blockIdx.x * 64;

    int arow = tid >> 2;            // 0..63
    int acol = (tid & 3) * 4;       // 0..12
    int brow = ty;                  // 0..15
    int bcol = tx * 4;              // 0..60

    float c[4][4] = {};

    for (int k0 = 0; k0 < K; k0 += 16) {
        float4 av = *(const float4*)&A[(size_t)(m0 + arow) * K + k0 + acol];
        size_t widx = wOff + (size_t)(k0 + brow) * N + n0 + bcol;
        float4 bv;
        if (f32) {
            bv = *(const float4*)((const float*)W + widx);
        } else {
            ushort4 wv = *(const ushort4*)((const unsigned short*)W + widx);
            bv = make_float4(bits2f(wv.x), bits2f(wv.y), bits2f(wv.z), bits2f(wv.w));
        }

        __syncthreads();
        *(float4*)&As[arow][acol] = av;
        *(float4*)&Bs[brow][bcol] = bv;
        __syncthreads();

#pragma unroll
        for (int k = 0; k < 16; ++k) {
            float a0 = As[ty][k], a1 = As[ty + 16][k], a2 = As[ty + 32][k], a3 = As[ty + 48][k];
            float b0 = Bs[k][tx], b1 = Bs[k][tx + 16], b2 = Bs[k][tx + 32], b3 = Bs[k][tx + 48];
            c[0][0] += a0 * b0; c[0][1] += a0 * b1; c[0][2] += a0 * b2; c[0][3] += a0 * b3;
            c[1][0] += a1 * b0; c[1][1] += a1 * b1; c[1][2] += a1 * b2; c[1][3] += a1 * b3;
            c[2][0] += a2 * b0; c[2][1] += a2 * b1; c[2][2] += a2 * b2; c[2][3] += a2 * b3;
            c[3][0] += a3 * b0; c[3][1] += a3 * b1; c[3][2] += a3 * b2; c[3][3] += a3 * b3;
        }
    }

#pragma unroll
    for (int i = 0; i < 4; ++i) {
        int m = m0 + ty + 16 * i;
#pragma unroll
        for (int j = 0; j < 4; ++j) {
            int n = n0 + tx + 16 * j;
            float v = c[i][j] + ldx(bias, bOff + n, f32);
            if (relu) v = fmaxf(v, 0.0f);
            C[(size_t)m * N + n] = v;
        }
    }
}

// ---------------------------------------------------------------------------
// Flash-style attention. One block per (64-q-row tile, head, batch).
// grid = (LD/64, H, B), 256 threads. K/V staged in LDS per 64-k tile and
// reused across all 64 q rows; online softmax (m,l,alpha per row in LDS).
// Causal blocks skip k-tiles with kt > qt.
__global__ __launch_bounds__(256) void fattn_kernel(
    const float* __restrict__ Q, const float* __restrict__ K,
    const float* __restrict__ V, float* __restrict__ O,
    const int* __restrict__ mask, int causal)
{
    __shared__ float Qs[64][36];    // row stride 36: float4-aligned, bank-shifted
    __shared__ float Ks[64][36];
    __shared__ float Vs[64][36];
    __shared__ float Ss[64][68];    // scores / probabilities tile
    __shared__ float mrow[64], lrow[64], arow[64];
    __shared__ int   smask[64];

    const int tid = threadIdx.x;
    const int qt = blockIdx.x, h = blockIdx.y, b = blockIdx.z;

    // --- loader mapping: 4 lanes per row, 8 floats per lane ---
    const int lr = tid >> 2;            // 0..63
    const int lc = (tid & 3) * 8;       // 0,8,16,24

    {
        const float* qp = Q + ((size_t)(b * LD_ + qt * 64 + lr)) * D_ + h * DK_ + lc;
        *(float4*)&Qs[lr][lc]     = *(const float4*)qp;
        *(float4*)&Qs[lr][lc + 4] = *(const float4*)(qp + 4);
    }
    if (tid < 64) { mrow[tid] = -3.0e38f; lrow[tid] = 0.0f; }

    // --- O accumulator mapping: rows rc, rc+32; cols cg..cg+3 ---
    const int rc = tid >> 3;            // 0..31
    const int cg = (tid & 7) * 4;       // 0,4,..,28
    float4 o0 = make_float4(0.f, 0.f, 0.f, 0.f);
    float4 o1 = make_float4(0.f, 0.f, 0.f, 0.f);

    // --- phase-A mapping: 16x16 thread grid, 4x4 micro-tile ---
    const int tx = tid & 15, ty = tid >> 4;
    // --- phase-B mapping: 4 consecutive lanes per row ---
    const int br = tid >> 2, bp = tid & 3;

    const int nkt = causal ? (qt + 1) : (LE_ / 64);
    const float scale = 0.17677669529663687f;   // 1/sqrt(32)

    for (int kt = 0; kt < nkt; ++kt) {
        __syncthreads();    // prior phase C done: K,V,S reusable
        {
            const float* kp = K + ((size_t)(b * LE_ + kt * 64 + lr)) * D_ + h * DK_ + lc;
            const float* vp = V + ((size_t)(b * LE_ + kt * 64 + lr)) * D_ + h * DK_ + lc;
            *(float4*)&Ks[lr][lc]     = *(const float4*)kp;
            *(float4*)&Ks[lr][lc + 4] = *(const float4*)(kp + 4);
            *(float4*)&Vs[lr][lc]     = *(const float4*)vp;
            *(float4*)&Vs[lr][lc + 4] = *(const float4*)(vp + 4);
        }
        if (tid < 64) smask[tid] = mask[b * 1024 + kt * 64 + tid];
        __syncthreads();

        // ---- phase A: S = Qs · Ks^T * scale (masked) ----
        float acc[4][4] = {};
#pragma unroll
        for (int k = 0; k < 32; k += 4) {
            float4 a0 = *(const float4*)&Qs[ty][k];
            float4 a1 = *(const float4*)&Qs[ty + 16][k];
            float4 a2 = *(const float4*)&Qs[ty + 32][k];
            float4 a3 = *(const float4*)&Qs[ty + 48][k];
            float4 b0 = *(const float4*)&Ks[tx][k];
            float4 b1 = *(const float4*)&Ks[tx + 16][k];
            float4 b2 = *(const float4*)&Ks[tx + 32][k];
            float4 b3 = *(const float4*)&Ks[tx + 48][k];
            acc[0][0] += dot4(a0, b0); acc[0][1] += dot4(a0, b1); acc[0][2] += dot4(a0, b2); acc[0][3] += dot4(a0, b3);
            acc[1][0] += dot4(a1, b0); acc[1][1] += dot4(a1, b1); acc[1][2] += dot4(a1, b2); acc[1][3] += dot4(a1, b3);
            acc[2][0] += dot4(a2, b0); acc[2][1] += dot4(a2, b1); acc[2][2] += dot4(a2, b2); acc[2][3] += dot4(a2, b3);
            acc[3][0] += dot4(a3, b0); acc[3][1] += dot4(a3, b1); acc[3][2] += dot4(a3, b2); acc[3][3] += dot4(a3, b3);
        }
#pragma unroll
        for (int i = 0; i < 4; ++i) {
            int row = ty + 16 * i;
            int qi = qt * 64 + row;
#pragma unroll
            for (int j = 0; j < 4; ++j) {
                int col = tx + 16 * j;
                int s = kt * 64 + col;
                bool msk = (causal && s > qi) || (smask[col] != 0);
                Ss[row][col] = msk ? -1e30f : acc[i][j] * scale;
            }
        }
        __syncthreads();

        // ---- phase B: online softmax update ----
        {
            float pm = -3.0e38f;
#pragma unroll
            for (int i = 0; i < 16; ++i) pm = fmaxf(pm, Ss[br][bp * 16 + i]);
            pm = fmaxf(pm, __shfl_xor(pm, 1));
            pm = fmaxf(pm, __shfl_xor(pm, 2));
            float mold = mrow[br];
            float mnew = fmaxf(mold, pm);
            float alpha = __expf(mold - mnew);
            float ps = 0.f;
#pragma unroll
            for (int i = 0; i < 16; ++i) {
                float e = __expf(Ss[br][bp * 16 + i] - mnew);
                Ss[br][bp * 16 + i] = e;
                ps += e;
            }
            ps += __shfl_xor(ps, 1);
            ps += __shfl_xor(ps, 2);
            if (bp == 0) {
                mrow[br] = mnew;
                lrow[br] = lrow[br] * alpha + ps;
                arow[br] = alpha;
            }
        }
        __syncthreads();

        // ---- phase C: O = O*alpha + P · V ----
        {
            float al0 = arow[rc], al1 = arow[rc + 32];
            o0.x *= al0; o0.y *= al0; o0.z *= al0; o0.w *= al0;
            o1.x *= al1; o1.y *= al1; o1.z *= al1; o1.w *= al1;
#pragma unroll 4
            for (int j = 0; j < 64; j += 4) {
                float4 p0 = *(const float4*)&Ss[rc][j];
                float4 p1 = *(const float4*)&Ss[rc + 32][j];
                float4 va = *(const float4*)&Vs[j][cg];
                float4 vb = *(const float4*)&Vs[j + 1][cg];
                float4 vc = *(const float4*)&Vs[j + 2][cg];
                float4 vd = *(const float4*)&Vs[j + 3][cg];
                o0.x += p0.x * va.x + p0.y * vb.x + p0.z * vc.x + p0.w * vd.x;
                o0.y += p0.x * va.y + p0.y * vb.y + p0.z * vc.y + p0.w * vd.y;
                o0.z += p0.x * va.z + p0.y * vb.z + p0.z * vc.z + p0.w * vd.z;
                o0.w += p0.x * va.w + p0.y * vb.w + p0.z * vc.w + p0.w * vd.w;
                o1.x += p1.x * va.x + p1.y * vb.x + p1.z * vc.x + p1.w * vd.x;
                o1.y += p1.x * va.y + p1.y * vb.y + p1.z * vc.y + p1.w * vd.y;
                o1.z += p1.x * va.z + p1.y * vb.z + p1.z * vc.z + p1.w * vd.z;
                o1.w += p1.x * va.w + p1.y * vb.w + p1.z * vc.w + p1.w * vd.w;
            }
        }
    }

    // ---- epilogue: normalize and store ----
    float inv0 = 1.0f / lrow[rc];
    float inv1 = 1.0f / lrow[rc + 32];
    float4 r0 = make_float4(o0.x * inv0, o0.y * inv0, o0.z * inv0, o0.w * inv0);
    float4 r1 = make_float4(o1.x * inv1, o1.y * inv1, o1.z * inv1, o1.w * inv1);
    *(float4*)&O[((size_t)(b * LD_ + qt * 64 + rc)) * D_ + h * DK_ + cg] = r0;
    *(float4*)&O[((size_t)(b * LD_ + qt * 64 + rc + 32)) * D_ + h * DK_ + cg] = r1;
}

// ---------------------------------------------------------------------------
// x = LayerNorm(t + x) * g + b ; g/b dtype per flag, gbOff = element offset
__global__ __launch_bounds__(256) void ln_res_kernel(
    const float* __restrict__ t, float* __restrict__ x,
    const void* __restrict__ g, const void* __restrict__ bt,
    size_t gbOff, const int* __restrict__ flag)
{
    __shared__ float r1[256];
    __shared__ float r2[256];
    int f32 = *flag;
    int tok = blockIdx.x;
    int d = threadIdx.x;
    size_t idx = (size_t)tok * D_ + d;
    float v = t[idx] + x[idx];
    r1[d] = v; r2[d] = v * v;
    __syncthreads();
    for (int off = 128; off > 0; off >>= 1) {
        if (d < off) { r1[d] += r1[d + off]; r2[d] += r2[d + off]; }
        __syncthreads();
    }
    float mean = r1[0] * (1.0f / 256.0f);
    float var  = r2[0] * (1.0f / 256.0f) - mean * mean;
    float inv  = 1.0f / sqrtf(var + 1e-5f);
    x[idx] = (v - mean) * inv * ldx(g, gbOff + d, f32) + ldx(bt, gbOff + d, f32);
}

__global__ __launch_bounds__(256) void cast_kernel(
    const float* __restrict__ x, void* __restrict__ out, const int* __restrict__ flag)
{
    int f32 = *flag;
    int i = blockIdx.x * 256 + threadIdx.x;
    if (f32) ((float*)out)[i] = x[i];
    else ((bf16*)out)[i] = __float2bfloat16(x[i]);
}

// ---------------------------------------------------------------------------
extern "C" void kernel_launch(void* const* d_in, const int* in_sizes, int n_in,
                              void* d_out, int out_size, void* d_ws, size_t ws_size,
                              hipStream_t stream)
{
    const void* enc       = d_in[0];
    const void* dec       = d_in[1];
    const int*  enc_masks = (const int*)d_in[2];
    const int*  dec_masks = (const int*)d_in[3];
    const void* W_tgt = d_in[4];
    const void* b_tgt = d_in[5];
    const void* sa_Wq = d_in[6];
    const void* sa_bq = d_in[7];
    const void* sa_Wk = d_in[8];
    const void* sa_bk = d_in[9];
    const void* sa_Wv = d_in[10];
    const void* sa_bv = d_in[11];
    const void* sa_Wo = d_in[12];
    const void* sa_bo = d_in[13];
    const void* sa_ln_g = d_in[14];
    const void* sa_ln_b = d_in[15];
    const void* ca_Wq = d_in[16];
    const void* ca_bq = d_in[17];
    const void* ca_Wk = d_in[18];
    const void* ca_bk = d_in[19];
    const void* ca_Wv = d_in[20];
    const void* ca_bv = d_in[21];
    const void* ca_Wo = d_in[22];
    const void* ca_bo = d_in[23];
    const void* ca_ln_g = d_in[24];
    const void* ca_ln_b = d_in[25];
    const void* ff_W1 = d_in[26];
    const void* ff_b1 = d_in[27];
    const void* ff_W2 = d_in[28];
    const void* ff_b2 = d_in[29];
    const void* ff_ln_g = d_in[30];
    const void* ff_ln_b = d_in[31];

    const size_t M1 = (size_t)NTOK * D_;        // 1M floats
    float* ws = (float*)d_ws;
    float* x     = ws;
    float* q     = ws + 1 * M1;
    float* k     = ws + 2 * M1;
    float* v     = ws + 3 * M1;
    float* ctx   = ws + 4 * M1;
    float* t     = ws + 5 * M1;
    float* h     = ws + 6 * M1;                 // 4M floats (NTOK x DFF)
    float* enc_f = ws + 10 * M1;
    int*   flag  = (int*)(ws + 11 * M1);

    const int nElem = NTOK * D_;                // 1,048,576

    detect_kernel<<<1, 256, 0, stream>>>(enc, flag);
    embed_kernel<<<nElem / 256, 256, 0, stream>>>(dec, W_tgt, b_tgt, x, flag);
    conv_kernel<<<nElem / 256, 256, 0, stream>>>(enc, enc_f, flag);

    dim3 gProj(D_ / 64, NTOK / 64, 3);          // (4,64,3)
    dim3 gOne(D_ / 64, NTOK / 64, 1);           // (4,64,1)
    dim3 gFF1(DFF_ / 64, NTOK / 64, 1);         // (16,64,1)
    dim3 gAttn(LD_ / 64, H_, B_);               // (16,8,4)

    for (int i = 0; i < NL_; ++i) {
        const size_t wOff  = (size_t)i * D_ * D_;      // element offsets
        const size_t bOff  = (size_t)i * D_;
        const size_t f1Off = (size_t)i * D_ * DFF_;
        const size_t f1bOff= (size_t)i * DFF_;

        add_pe_kernel<<<nElem / 256, 256, 0, stream>>>(x);

        // --- self attention ---
        gemm3_kernel<<<gProj, 256, 0, stream>>>(
            x, x, x, sa_Wq, sa_Wk, sa_Wv, sa_bq, sa_bk, sa_bv,
            q, k, v, wOff, bOff, NTOK, D_, D_, 0, flag);
        fattn_kernel<<<gAttn, 256, 0, stream>>>(q, k, v, ctx, dec_masks, 1);
        gemm3_kernel<<<gOne, 256, 0, stream>>>(
            ctx, ctx, ctx, sa_Wo, sa_Wo, sa_Wo, sa_bo, sa_bo, sa_bo,
            t, t, t, wOff, bOff, NTOK, D_, D_, 0, flag);
        ln_res_kernel<<<NTOK, 256, 0, stream>>>(t, x, sa_ln_g, sa_ln_b, bOff, flag);

        // --- cross attention ---
        gemm3_kernel<<<gProj, 256, 0, stream>>>(
            x, enc_f, enc_f, ca_Wq, ca_Wk, ca_Wv, ca_bq, ca_bk, ca_bv,
            q, k, v, wOff, bOff, NTOK, D_, D_, 0, flag);
        fattn_kernel<<<gAttn, 256, 0, stream>>>(q, k, v, ctx, enc_masks, 0);
        gemm3_kernel<<<gOne, 256, 0, stream>>>(
            ctx, ctx, ctx, ca_Wo, ca_Wo, ca_Wo, ca_bo, ca_bo, ca_bo,
            t, t, t, wOff, bOff, NTOK, D_, D_, 0, flag);
        ln_res_kernel<<<NTOK, 256, 0, stream>>>(t, x, ca_ln_g, ca_ln_b, bOff, flag);

        // --- FFN ---
        gemm3_kernel<<<gFF1, 256, 0, stream>>>(
            x, x, x, ff_W1, ff_W1, ff_W1, ff_b1, ff_b1, ff_b1,
            h, h, h, f1Off, f1bOff, NTOK, DFF_, D_, 1, flag);
        gemm3_kernel<<<gOne, 256, 0, stream>>>(
            h, h, h, ff_W2, ff_W2, ff_W2, ff_b2, ff_b2, ff_b2,
            t, t, t, f1Off, bOff, NTOK, D_, DFF_, 0, flag);
        ln_res_kernel<<<NTOK, 256, 0, stream>>>(t, x, ff_ln_g, ff_ln_b, bOff, flag);
    }

    cast_kernel<<<nElem / 256, 256, 0, stream>>>(x, d_out, flag);
}